// Round 1
// baseline (10083.361 us; speedup 1.0000x reference)
//
#include <hip/hip_runtime.h>
#include <hip/hip_bf16.h>
#include <math.h>

#define NNODES 50000
#define NEDGES 1600000

// ---------------- CSR build ----------------
__global__ void k_init_counts(int* cnt_d, int* cnt_t, int n){
  int i = blockIdx.x*blockDim.x + threadIdx.x;
  if (i < n){ cnt_d[i] = 0; cnt_t[i] = 0; }
}

__global__ void k_count(const int* __restrict__ ei, int* __restrict__ cnt, int e){
  int i = blockIdx.x*blockDim.x + threadIdx.x;
  if (i < e) atomicAdd(&cnt[ei[e + i]], 1);   // dst row = ei[E + i]
}

// single-block exclusive scan over n counts -> rowptr, cursor copy, dinv
__global__ __launch_bounds__(1024) void k_scan(const int* __restrict__ cnt,
    int* __restrict__ rowptr, int* __restrict__ cur, float* __restrict__ dinv, int n){
  __shared__ int sdata[1024];
  __shared__ int s_run;
  const int tid = threadIdx.x;
  if (tid == 0) s_run = 0;
  __syncthreads();
  for (int base = 0; base < n; base += 1024){
    int i = base + tid;
    int v = (i < n) ? cnt[i] : 0;
    sdata[tid] = v;
    __syncthreads();
    for (int off = 1; off < 1024; off <<= 1){
      int t = (tid >= off) ? sdata[tid - off] : 0;
      __syncthreads();
      sdata[tid] += t;
      __syncthreads();
    }
    int excl = sdata[tid] - v;
    int run = s_run;
    if (i < n){
      rowptr[i] = run + excl;
      cur[i]    = run + excl;
      dinv[i]   = 1.0f / sqrtf(1.0f + (float)v);  // deg = 1 + in-degree
    }
    __syncthreads();
    if (tid == 1023) s_run = run + sdata[1023];
    __syncthreads();
  }
  if (tid == 0) rowptr[n] = s_run;
}

__global__ void k_fill(const int* __restrict__ ei, int* __restrict__ cur,
                       int* __restrict__ col, float* __restrict__ w,
                       const float* __restrict__ dinv, int e){
  int i = blockIdx.x*blockDim.x + threadIdx.x;
  if (i < e){
    int src = ei[i], dst = ei[e + i];
    int pos = atomicAdd(&cur[dst], 1);
    col[pos] = src;
    w[pos]   = dinv[src];
  }
}

// ---------------- fp32 tiled GEMM: C[M,N] = A[M,K] @ B[K,N] (+bias)(+relu) ----------------
// block tile 64x64, 256 threads, 4x4 per-thread microtile, BK=16.
// Requires N % 64 == 0 and K % 16 == 0 (holds for all calls here); M guarded.
__global__ __launch_bounds__(256) void gemm_f32(
    const float* __restrict__ A, const float* __restrict__ B,
    const float* __restrict__ bias, float* __restrict__ C,
    int M, int N, int K, int relu)
{
  __shared__ float As[16][68];   // [k][m], +4 pad keeps 16B alignment, kills conflicts
  __shared__ float Bs[16][68];   // [k][n]
  const int tid = threadIdx.x;
  const int bm = blockIdx.y * 64;
  const int bn = blockIdx.x * 64;
  const int tx = tid & 15;          // n-quad
  const int ty = tid >> 4;          // m-quad
  const int kA = tid & 15, mA0 = tid >> 4;
  const int nB = tid & 63, kB0 = tid >> 6;
  float acc[4][4] = {};
  for (int k0 = 0; k0 < K; k0 += 16){
    #pragma unroll
    for (int i = 0; i < 4; i++){
      int m = bm + mA0 + 16*i;
      As[kA][mA0 + 16*i] = (m < M) ? A[(size_t)m*K + (k0 + kA)] : 0.f;
    }
    #pragma unroll
    for (int i = 0; i < 4; i++){
      int k = kB0 + 4*i;
      Bs[k][nB] = B[(size_t)(k0 + k)*N + (bn + nB)];
    }
    __syncthreads();
    #pragma unroll
    for (int kk = 0; kk < 16; kk++){
      float4 a = *(const float4*)&As[kk][ty*4];
      float4 b = *(const float4*)&Bs[kk][tx*4];
      acc[0][0] += a.x*b.x; acc[0][1] += a.x*b.y; acc[0][2] += a.x*b.z; acc[0][3] += a.x*b.w;
      acc[1][0] += a.y*b.x; acc[1][1] += a.y*b.y; acc[1][2] += a.y*b.z; acc[1][3] += a.y*b.w;
      acc[2][0] += a.z*b.x; acc[2][1] += a.z*b.y; acc[2][2] += a.z*b.z; acc[2][3] += a.z*b.w;
      acc[3][0] += a.w*b.x; acc[3][1] += a.w*b.y; acc[3][2] += a.w*b.z; acc[3][3] += a.w*b.w;
    }
    __syncthreads();
  }
  #pragma unroll
  for (int i = 0; i < 4; i++){
    int m = bm + ty*4 + i;
    if (m < M){
      #pragma unroll
      for (int j = 0; j < 4; j++){
        int n = bn + tx*4 + j;
        float v = acc[i][j] + (bias ? bias[n] : 0.f);
        if (relu) v = fmaxf(v, 0.f);
        C[(size_t)m*N + n] = v;
      }
    }
  }
}

// ---------------- GCN aggregation (CSR gather, F=512) ----------------
// out[dst] = dinv[dst] * sum_{src in N(dst)} dinv[src]*H[src] + dinv[dst]^2*H[dst] + bias
__global__ __launch_bounds__(256) void k_agg(
    const float* __restrict__ H, const int* __restrict__ rowptr,
    const int* __restrict__ col, const float* __restrict__ w,
    const float* __restrict__ dinv, const float* __restrict__ bias,
    float* __restrict__ out)
{
  const int row = blockIdx.x;
  const int f = threadIdx.x * 2;
  const int beg = rowptr[row], end = rowptr[row+1];
  float ax = 0.f, ay = 0.f;
  for (int e = beg; e < end; e++){
    int s    = col[e];
    float ws = w[e];
    float2 h = *(const float2*)&H[(size_t)s*512 + f];
    ax += ws*h.x; ay += ws*h.y;
  }
  float di  = dinv[row];
  float2 hs = *(const float2*)&H[(size_t)row*512 + f];
  float ox = di*ax + di*di*hs.x + bias[f];
  float oy = di*ay + di*di*hs.y + bias[f+1];
  *(float2*)&out[(size_t)row*512 + f] = make_float2(ox, oy);
}

// ---------------- cosine + sigmoid, one wave per row ----------------
__global__ __launch_bounds__(256) void k_cos(const float* __restrict__ a,
    const float* __restrict__ b, float* __restrict__ out, int n)
{
  const int lane = threadIdx.x & 63;
  const int wid  = threadIdx.x >> 6;
  const int row  = blockIdx.x*4 + wid;
  if (row >= n) return;
  const float4* pa = (const float4*)&a[(size_t)row*512];
  const float4* pb = (const float4*)&b[(size_t)row*512];
  float dot = 0.f, na = 0.f, nb = 0.f;
  #pragma unroll
  for (int j = 0; j < 2; j++){
    float4 x = pa[lane + 64*j];
    float4 y = pb[lane + 64*j];
    dot += x.x*y.x + x.y*y.y + x.z*y.z + x.w*y.w;
    na  += x.x*x.x + x.y*x.y + x.z*x.z + x.w*x.w;
    nb  += y.x*y.x + y.y*y.y + y.z*y.z + y.w*y.w;
  }
  #pragma unroll
  for (int off = 32; off > 0; off >>= 1){
    dot += __shfl_down(dot, off);
    na  += __shfl_down(na , off);
    nb  += __shfl_down(nb , off);
  }
  if (lane == 0){
    float dn = fmaxf(sqrtf(na), 1e-8f);
    float tn = fmaxf(sqrtf(nb), 1e-8f);
    float c  = dot / (dn * tn);
    out[row] = 1.0f / (1.0f + expf(-c));
  }
}

extern "C" void kernel_launch(void* const* d_in, const int* in_sizes, int n_in,
                              void* d_out, int out_size, void* d_ws, size_t ws_size,
                              hipStream_t stream)
{
  (void)in_sizes; (void)n_in; (void)out_size; (void)ws_size;
  const float* drug   = (const float*)d_in[0];   // [50000,2048]
  const float* target = (const float*)d_in[1];   // [50000,1024]
  const int*   ei_d   = (const int*)d_in[2];     // [2,E]
  const int*   ei_t   = (const int*)d_in[3];
  const float* Wd = (const float*)d_in[4];       // [2048,1024]
  const float* bd = (const float*)d_in[5];
  const float* Wt = (const float*)d_in[6];       // [1024,1024]
  const float* bt = (const float*)d_in[7];
  const float* W1 = (const float*)d_in[8];       // [1024,512]
  const float* b1 = (const float*)d_in[9];
  const float* W2 = (const float*)d_in[10];      // [512,512]
  const float* b2 = (const float*)d_in[11];
  float* out = (float*)d_out;

  const int n = NNODES, E = NEDGES;
  char* ws = (char*)d_ws;
  size_t off = 0;
  auto alloc = [&](size_t bytes)->char* {
    char* p = ws + off; off += (bytes + 255) & ~(size_t)255; return p;
  };
  int*   cnt_d  = (int*)  alloc((size_t)n*4);
  int*   cnt_t  = (int*)  alloc((size_t)n*4);
  int*   rp_d   = (int*)  alloc((size_t)(n+1)*4);
  int*   rp_t   = (int*)  alloc((size_t)(n+1)*4);
  int*   cur_d  = (int*)  alloc((size_t)n*4);
  int*   cur_t  = (int*)  alloc((size_t)n*4);
  int*   col_d  = (int*)  alloc((size_t)E*4);
  int*   col_t  = (int*)  alloc((size_t)E*4);
  float* w_d    = (float*)alloc((size_t)E*4);
  float* w_t    = (float*)alloc((size_t)E*4);
  float* dinv_d = (float*)alloc((size_t)n*4);
  float* dinv_t = (float*)alloc((size_t)n*4);
  const int STRIPE = 10000;                       // 5 stripes of 10000 rows
  float* bufP = (float*)alloc((size_t)STRIPE*1024*4);  // projection stripe
  float* bufH = (float*)alloc((size_t)n*512*4);        // H (matmul out)
  float* bufC = (float*)alloc((size_t)n*512*4);        // dp (drug keeps dp2 here)
  float* bufD = (float*)alloc((size_t)n*512*4);        // dp (target)

  dim3 blk(256);

  // ---- CSR build (both graphs) ----
  k_init_counts<<<(n+255)/256, blk, 0, stream>>>(cnt_d, cnt_t, n);
  k_count<<<(E+255)/256, blk, 0, stream>>>(ei_d, cnt_d, E);
  k_count<<<(E+255)/256, blk, 0, stream>>>(ei_t, cnt_t, E);
  k_scan<<<1, 1024, 0, stream>>>(cnt_d, rp_d, cur_d, dinv_d, n);
  k_scan<<<1, 1024, 0, stream>>>(cnt_t, rp_t, cur_t, dinv_t, n);
  k_fill<<<(E+255)/256, blk, 0, stream>>>(ei_d, cur_d, col_d, w_d, dinv_d, E);
  k_fill<<<(E+255)/256, blk, 0, stream>>>(ei_t, cur_t, col_t, w_t, dinv_t, E);

  // ---- drug pipeline ----
  for (int s = 0; s < 5; s++){
    dim3 g1(1024/64, (STRIPE+63)/64);
    gemm_f32<<<g1, blk, 0, stream>>>(drug + (size_t)s*STRIPE*2048, Wd, bd, bufP,
                                     STRIPE, 1024, 2048, 1);
    dim3 g2(512/64, (STRIPE+63)/64);
    gemm_f32<<<g2, blk, 0, stream>>>(bufP, W1, nullptr, bufH + (size_t)s*STRIPE*512,
                                     STRIPE, 512, 1024, 0);
  }
  k_agg<<<n, blk, 0, stream>>>(bufH, rp_d, col_d, w_d, dinv_d, b1, bufC);  // dp1
  { dim3 g(512/64, (n+63)/64);
    gemm_f32<<<g, blk, 0, stream>>>(bufC, W2, nullptr, bufH, n, 512, 512, 0); } // H2
  k_agg<<<n, blk, 0, stream>>>(bufH, rp_d, col_d, w_d, dinv_d, b2, bufC);  // dp2 (drug)

  // ---- target pipeline ----
  for (int s = 0; s < 5; s++){
    dim3 g1(1024/64, (STRIPE+63)/64);
    gemm_f32<<<g1, blk, 0, stream>>>(target + (size_t)s*STRIPE*1024, Wt, bt, bufP,
                                     STRIPE, 1024, 1024, 1);
    dim3 g2(512/64, (STRIPE+63)/64);
    gemm_f32<<<g2, blk, 0, stream>>>(bufP, W1, nullptr, bufH + (size_t)s*STRIPE*512,
                                     STRIPE, 512, 1024, 0);
  }
  k_agg<<<n, blk, 0, stream>>>(bufH, rp_t, col_t, w_t, dinv_t, b1, bufD);  // dp1
  { dim3 g(512/64, (n+63)/64);
    gemm_f32<<<g, blk, 0, stream>>>(bufD, W2, nullptr, bufH, n, 512, 512, 0); } // H2
  k_agg<<<n, blk, 0, stream>>>(bufH, rp_t, col_t, w_t, dinv_t, b2, bufD);  // dp2 (target)

  // ---- cosine + sigmoid ----
  k_cos<<<(n+3)/4, blk, 0, stream>>>(bufC, bufD, out, n);
}

// Round 2
// 3382.945 us; speedup vs baseline: 2.9806x; 2.9806x over previous
//
#include <hip/hip_runtime.h>
#include <math.h>

#define NNODES 50000
#define NEDGES 1600000
#define MP 50048   // 391 * 128, padded row count

typedef unsigned int uint_t;
typedef __attribute__((ext_vector_type(8))) short short8;
typedef __attribute__((ext_vector_type(4))) float f32x4;

__device__ __forceinline__ unsigned short f2bf(float f){
  union { float f; uint_t u; } v; v.f = f;
  uint_t u = v.u;
  uint_t r = (u + 0x7fffu + ((u >> 16) & 1u)) >> 16;   // RNE
  return (unsigned short)r;
}
__device__ __forceinline__ float bf2f(uint_t u){
  union { uint_t u; float f; } v; v.u = u << 16;
  return v.f;
}

// ---------------- CSR build ----------------
__global__ void k_init_counts(int* cnt_d, int* cnt_t, int n){
  int i = blockIdx.x*blockDim.x + threadIdx.x;
  if (i < n){ cnt_d[i] = 0; cnt_t[i] = 0; }
}

__global__ void k_count(const int* __restrict__ ei, int* __restrict__ cnt, int e){
  int i = blockIdx.x*blockDim.x + threadIdx.x;
  if (i < e) atomicAdd(&cnt[ei[e + i]], 1);   // dst row = ei[E + i]
}

__global__ __launch_bounds__(1024) void k_scan(const int* __restrict__ cnt,
    int* __restrict__ rowptr, int* __restrict__ cur, float* __restrict__ dinv, int n){
  __shared__ int sdata[1024];
  __shared__ int s_run;
  const int tid = threadIdx.x;
  if (tid == 0) s_run = 0;
  __syncthreads();
  for (int base = 0; base < n; base += 1024){
    int i = base + tid;
    int v = (i < n) ? cnt[i] : 0;
    sdata[tid] = v;
    __syncthreads();
    for (int off = 1; off < 1024; off <<= 1){
      int t = (tid >= off) ? sdata[tid - off] : 0;
      __syncthreads();
      sdata[tid] += t;
      __syncthreads();
    }
    int excl = sdata[tid] - v;
    int run = s_run;
    if (i < n){
      rowptr[i] = run + excl;
      cur[i]    = run + excl;
      dinv[i]   = 1.0f / sqrtf(1.0f + (float)v);
    }
    __syncthreads();
    if (tid == 1023) s_run = run + sdata[1023];
    __syncthreads();
  }
  if (tid == 0) rowptr[n] = s_run;
}

__global__ void k_fill(const int* __restrict__ ei, int* __restrict__ cur,
                       int* __restrict__ col, float* __restrict__ w,
                       const float* __restrict__ dinv, int e){
  int i = blockIdx.x*blockDim.x + threadIdx.x;
  if (i < e){
    int src = ei[i], dst = ei[e + i];
    int pos = atomicAdd(&cur[dst], 1);
    col[pos] = src;
    w[pos]   = dinv[src];
  }
}

// ---------------- cast fp32 -> bf16 (flat, zero-pad tail) ----------------
__global__ void k_cast_bf(const float* __restrict__ src, unsigned short* __restrict__ dst,
                          long long n_src, long long n_total){
  long long i = ((long long)blockIdx.x * 256 + threadIdx.x) * 4;
  if (i >= n_total) return;
  ushort4 o;
  if (i < n_src){
    float4 v = *(const float4*)&src[i];
    o.x = f2bf(v.x); o.y = f2bf(v.y); o.z = f2bf(v.z); o.w = f2bf(v.w);
  } else { o.x = 0; o.y = 0; o.z = 0; o.w = 0; }
  *(ushort4*)&dst[i] = o;
}

// ---------------- transpose + cast: W[K,N] fp32 -> WT[N,K] bf16 ----------------
__global__ __launch_bounds__(256) void k_tr_cast(const float* __restrict__ W,
    unsigned short* __restrict__ WT, int K, int N){
  __shared__ float t[32][33];
  int bx = blockIdx.x * 32;   // N dim
  int by = blockIdx.y * 32;   // K dim
  int x = threadIdx.x & 31, y0 = threadIdx.x >> 5;
  for (int y = y0; y < 32; y += 8)
    t[y][x] = W[(size_t)(by + y)*N + bx + x];
  __syncthreads();
  for (int y = y0; y < 32; y += 8)
    WT[(size_t)(bx + y)*K + by + x] = f2bf(t[x][y]);
}

// ---------------- bf16 MFMA GEMM: C[MP,N] = A[MP,K] @ BT[N,K]^T ----------------
// 128x128 block tile, BK=32, 256 threads (4 waves), 4x4 16x16x32 MFMA per wave.
// global_load_lds width=16 staging; XOR swizzle keeps ds_read_b128 conflicts <=2-way.
__global__ __launch_bounds__(256) void gemm_bf16(
    const unsigned short* __restrict__ A, const unsigned short* __restrict__ BT,
    const float* __restrict__ bias, void* __restrict__ Cv,
    int N, int K, int relu, int out_bf16)
{
  __shared__ unsigned short As[128*32];
  __shared__ unsigned short Bs[128*32];
  const int tid  = threadIdx.x;
  const int lane = tid & 63;
  const int wave = tid >> 6;
  const long long bm = (long long)blockIdx.y * 128;
  const int bn = blockIdx.x * 128;
  const int wm = (wave & 1) * 64;
  const int wn = (wave >> 1) * 64;
  // staging: lane i covers LDS slot (row = wave*32 + t*16 + i/4, colgroup = i%4)
  const int srow = lane >> 2;
  const int sg   = lane & 3;
  const int gcol = (sg ^ ((srow >> 1) & 3)) * 8;   // swizzled global col group
  const unsigned short* pa0 = A  + (bm + wave*32 + srow) * K + gcol;
  const unsigned short* pb0 = BT + (long long)(bn + wave*32 + srow) * K + gcol;
  unsigned short* lA0 = As + (wave*32     )*32;
  unsigned short* lA1 = As + (wave*32 + 16)*32;
  unsigned short* lB0 = Bs + (wave*32     )*32;
  unsigned short* lB1 = Bs + (wave*32 + 16)*32;

  const int lm = lane & 15;
  const int q  = lane >> 4;
  const int fcol = ((q ^ ((lm >> 1) & 3)) * 8);    // swizzled LDS col group for frags

  f32x4 acc[4][4] = {};

  for (int k0 = 0; k0 < K; k0 += 32){
    __builtin_amdgcn_global_load_lds((const __attribute__((address_space(1))) void*)(pa0 + k0),
        (__attribute__((address_space(3))) void*)lA0, 16, 0, 0);
    __builtin_amdgcn_global_load_lds((const __attribute__((address_space(1))) void*)(pa0 + 16*K + k0),
        (__attribute__((address_space(3))) void*)lA1, 16, 0, 0);
    __builtin_amdgcn_global_load_lds((const __attribute__((address_space(1))) void*)(pb0 + k0),
        (__attribute__((address_space(3))) void*)lB0, 16, 0, 0);
    __builtin_amdgcn_global_load_lds((const __attribute__((address_space(1))) void*)(pb0 + 16*K + k0),
        (__attribute__((address_space(3))) void*)lB1, 16, 0, 0);
    __syncthreads();
    short8 af[4], bfr[4];
    #pragma unroll
    for (int i = 0; i < 4; i++){
      af[i]  = *(const short8*)&As[(wm + 16*i + lm)*32 + fcol];
      bfr[i] = *(const short8*)&Bs[(wn + 16*i + lm)*32 + fcol];
    }
    #pragma unroll
    for (int i = 0; i < 4; i++)
      #pragma unroll
      for (int j = 0; j < 4; j++)
        acc[i][j] = __builtin_amdgcn_mfma_f32_16x16x32_bf16(af[i], bfr[j], acc[i][j], 0, 0, 0);
    __syncthreads();
  }

  // epilogue: D[m = q*4 + r (within 16-tile), n = lm]
  #pragma unroll
  for (int j = 0; j < 4; j++){
    int c = bn + wn + 16*j + lm;
    float bv = bias ? bias[c] : 0.f;
    #pragma unroll
    for (int i = 0; i < 4; i++){
      long long mrow = bm + wm + 16*i + q*4;
      #pragma unroll
      for (int r = 0; r < 4; r++){
        float v = acc[i][j][r] + bv;
        if (relu) v = fmaxf(v, 0.f);
        if (out_bf16) ((unsigned short*)Cv)[(mrow + r)*N + c] = f2bf(v);
        else          ((float*)Cv)[(mrow + r)*N + c] = v;
      }
    }
  }
}

// ---------------- GCN aggregation (CSR gather, F=512, bf16 in/out) ----------------
__global__ __launch_bounds__(256) void k_agg_bf(
    const unsigned short* __restrict__ H, const int* __restrict__ rowptr,
    const int* __restrict__ col, const float* __restrict__ w,
    const float* __restrict__ dinv, const float* __restrict__ bias,
    unsigned short* __restrict__ out)
{
  const int row = blockIdx.x;
  const int f = threadIdx.x * 2;
  const int beg = rowptr[row], end = rowptr[row+1];
  float ax = 0.f, ay = 0.f;
  for (int e = beg; e < end; e++){
    int s = col[e]; float ws = w[e];
    uint_t h = *(const uint_t*)&H[(size_t)s*512 + f];
    ax += ws * bf2f(h & 0xffffu);
    ay += ws * bf2f(h >> 16);
  }
  float di = dinv[row];
  uint_t hs = *(const uint_t*)&H[(size_t)row*512 + f];
  float ox = di*ax + di*di*bf2f(hs & 0xffffu) + bias[f];
  float oy = di*ay + di*di*bf2f(hs >> 16) + bias[f+1];
  uint_t o = (uint_t)f2bf(ox) | ((uint_t)f2bf(oy) << 16);
  *(uint_t*)&out[(size_t)row*512 + f] = o;
}

// ---------------- cosine + sigmoid (bf16 in), one wave per row ----------------
__global__ __launch_bounds__(256) void k_cos_bf(const unsigned short* __restrict__ a,
    const unsigned short* __restrict__ b, float* __restrict__ out, int n)
{
  const int lane = threadIdx.x & 63;
  const int wid  = threadIdx.x >> 6;
  const int row  = blockIdx.x*4 + wid;
  if (row >= n) return;
  uint4 x = *(const uint4*)&a[(size_t)row*512 + lane*8];
  uint4 y = *(const uint4*)&b[(size_t)row*512 + lane*8];
  uint_t xs[4] = {x.x, x.y, x.z, x.w};
  uint_t ys[4] = {y.x, y.y, y.z, y.w};
  float dot = 0.f, na = 0.f, nb = 0.f;
  #pragma unroll
  for (int k = 0; k < 4; k++){
    float x0 = bf2f(xs[k] & 0xffffu), x1 = bf2f(xs[k] >> 16);
    float y0 = bf2f(ys[k] & 0xffffu), y1 = bf2f(ys[k] >> 16);
    dot += x0*y0 + x1*y1;
    na  += x0*x0 + x1*x1;
    nb  += y0*y0 + y1*y1;
  }
  #pragma unroll
  for (int off = 32; off; off >>= 1){
    dot += __shfl_down(dot, off);
    na  += __shfl_down(na , off);
    nb  += __shfl_down(nb , off);
  }
  if (lane == 0){
    float dn = fmaxf(sqrtf(na), 1e-8f);
    float tn = fmaxf(sqrtf(nb), 1e-8f);
    out[row] = 1.f/(1.f + expf(-dot/(dn*tn)));
  }
}

extern "C" void kernel_launch(void* const* d_in, const int* in_sizes, int n_in,
                              void* d_out, int out_size, void* d_ws, size_t ws_size,
                              hipStream_t stream)
{
  (void)in_sizes; (void)n_in; (void)out_size; (void)ws_size;
  const float* drug   = (const float*)d_in[0];   // [50000,2048]
  const float* target = (const float*)d_in[1];   // [50000,1024]
  const int*   ei_d   = (const int*)d_in[2];
  const int*   ei_t   = (const int*)d_in[3];
  const float* Wd = (const float*)d_in[4];       // [2048,1024]
  const float* bd = (const float*)d_in[5];
  const float* Wt = (const float*)d_in[6];       // [1024,1024]
  const float* bt = (const float*)d_in[7];
  const float* W1 = (const float*)d_in[8];       // [1024,512]
  const float* b1 = (const float*)d_in[9];
  const float* W2 = (const float*)d_in[10];      // [512,512]
  const float* b2 = (const float*)d_in[11];
  float* out = (float*)d_out;

  const int n = NNODES, E = NEDGES;
  char* ws = (char*)d_ws;
  size_t off = 0;
  auto alloc = [&](size_t bytes)->char* {
    char* p = ws + off; off += (bytes + 255) & ~(size_t)255; return p;
  };
  int*   cnt_d  = (int*)  alloc((size_t)n*4);
  int*   cnt_t  = (int*)  alloc((size_t)n*4);
  int*   rp_d   = (int*)  alloc((size_t)(n+1)*4);
  int*   rp_t   = (int*)  alloc((size_t)(n+1)*4);
  int*   cur_d  = (int*)  alloc((size_t)n*4);
  int*   cur_t  = (int*)  alloc((size_t)n*4);
  int*   col_d  = (int*)  alloc((size_t)E*4);
  int*   col_t  = (int*)  alloc((size_t)E*4);
  float* w_d    = (float*)alloc((size_t)E*4);
  float* w_t    = (float*)alloc((size_t)E*4);
  float* dinv_d = (float*)alloc((size_t)n*4);
  float* dinv_t = (float*)alloc((size_t)n*4);
  unsigned short* WdT = (unsigned short*)alloc((size_t)1024*2048*2);
  unsigned short* WtT = (unsigned short*)alloc((size_t)1024*1024*2);
  unsigned short* W1T = (unsigned short*)alloc((size_t)512*1024*2);
  unsigned short* W2T = (unsigned short*)alloc((size_t)512*512*2);
  unsigned short* bufA = (unsigned short*)alloc((size_t)MP*2048*2); // drug, then target
  unsigned short* bufP = (unsigned short*)alloc((size_t)MP*1024*2);
  unsigned short* bufH = (unsigned short*)alloc((size_t)MP*512*2);
  unsigned short* dp1  = (unsigned short*)alloc((size_t)MP*512*2);
  unsigned short* dp2d = (unsigned short*)alloc((size_t)MP*512*2);
  unsigned short* dp2t = (unsigned short*)alloc((size_t)MP*512*2);

  dim3 blk(256);

  // ---- CSR build ----
  k_init_counts<<<(n+255)/256, blk, 0, stream>>>(cnt_d, cnt_t, n);
  k_count<<<(E+255)/256, blk, 0, stream>>>(ei_d, cnt_d, E);
  k_count<<<(E+255)/256, blk, 0, stream>>>(ei_t, cnt_t, E);
  k_scan<<<1, 1024, 0, stream>>>(cnt_d, rp_d, cur_d, dinv_d, n);
  k_scan<<<1, 1024, 0, stream>>>(cnt_t, rp_t, cur_t, dinv_t, n);
  k_fill<<<(E+255)/256, blk, 0, stream>>>(ei_d, cur_d, col_d, w_d, dinv_d, E);
  k_fill<<<(E+255)/256, blk, 0, stream>>>(ei_t, cur_t, col_t, w_t, dinv_t, E);

  // ---- weights: transpose + cast ----
  k_tr_cast<<<dim3(1024/32, 2048/32), blk, 0, stream>>>(Wd, WdT, 2048, 1024);
  k_tr_cast<<<dim3(1024/32, 1024/32), blk, 0, stream>>>(Wt, WtT, 1024, 1024);
  k_tr_cast<<<dim3( 512/32, 1024/32), blk, 0, stream>>>(W1, W1T, 1024,  512);
  k_tr_cast<<<dim3( 512/32,  512/32), blk, 0, stream>>>(W2, W2T,  512,  512);

  // ---- drug pipeline ----
  {
    long long nsrc = (long long)n*2048, ntot = (long long)MP*2048;
    k_cast_bf<<<(unsigned)((ntot/4 + 255)/256), blk, 0, stream>>>(drug, bufA, nsrc, ntot);
  }
  gemm_bf16<<<dim3(8, MP/128), blk, 0, stream>>>(bufA, WdT, bd, bufP, 1024, 2048, 1, 1);
  gemm_bf16<<<dim3(4, MP/128), blk, 0, stream>>>(bufP, W1T, nullptr, bufH, 512, 1024, 0, 1);
  k_agg_bf<<<n, blk, 0, stream>>>(bufH, rp_d, col_d, w_d, dinv_d, b1, dp1);
  gemm_bf16<<<dim3(4, MP/128), blk, 0, stream>>>(dp1, W2T, nullptr, bufH, 512, 512, 0, 1);
  k_agg_bf<<<n, blk, 0, stream>>>(bufH, rp_d, col_d, w_d, dinv_d, b2, dp2d);

  // ---- target pipeline ----
  {
    long long nsrc = (long long)n*1024, ntot = (long long)MP*1024;
    k_cast_bf<<<(unsigned)((ntot/4 + 255)/256), blk, 0, stream>>>(target, bufA, nsrc, ntot);
  }
  gemm_bf16<<<dim3(8, MP/128), blk, 0, stream>>>(bufA, WtT, bt, bufP, 1024, 1024, 1, 1);
  gemm_bf16<<<dim3(4, MP/128), blk, 0, stream>>>(bufP, W1T, nullptr, bufH, 512, 1024, 0, 1);
  k_agg_bf<<<n, blk, 0, stream>>>(bufH, rp_t, col_t, w_t, dinv_t, b1, dp1);
  gemm_bf16<<<dim3(4, MP/128), blk, 0, stream>>>(dp1, W2T, nullptr, bufH, 512, 512, 0, 1);
  k_agg_bf<<<n, blk, 0, stream>>>(bufH, rp_t, col_t, w_t, dinv_t, b2, dp2t);

  // ---- cosine + sigmoid ----
  k_cos_bf<<<(n+3)/4, blk, 0, stream>>>(dp2d, dp2t, out, n);
}